// Round 1
// baseline (130.832 us; speedup 1.0000x reference)
//
#include <hip/hip_runtime.h>

// Problem constants (B=2, H=8, L=1024, D=64)
#define N_HEADS 16          // B*H
#define L_SEQ   1024
#define D_HEAD  64
#define D2      128         // 2*D (sin/cos concat)
#define T_CHUNK 64
#define N_CHUNK (L_SEQ / T_CHUNK)   // 16
#define KV_ELEMS (D2 * D_HEAD)      // 8192

// Padded LDS row: insert a 4-float gap every 32 columns so the 4 g-groups
// (float4 reads at 32g-float offsets) land on distinct banks.
// col' = d2 + 4*(d2>>5); row length = 128 + 12 = 140 floats.
#define ROWP 140

__device__ __forceinline__ int pad_col(int d2) { return d2 + 4 * (d2 >> 5); }

#define HALF_PI 1.57079632679489662f

// ---------------------------------------------------------------------------
// K1: per-(chunk, head) local sums:  sumkv[d2][m] = sum_l k_[l][d2]*v[l][m]
//                                    sumk[d2]     = sum_l k_[l][d2]
// ---------------------------------------------------------------------------
__global__ __launch_bounds__(256) void k1_chunk_sums(
    const float* __restrict__ k, const float* __restrict__ v,
    float* __restrict__ sumkv, float* __restrict__ sumk)
{
    __shared__ float k_s[T_CHUNK][ROWP];
    __shared__ float v_s[T_CHUNK][D_HEAD];

    const int c = blockIdx.x, n = blockIdx.y;
    const int tid = threadIdx.x;
    const int base = (n * L_SEQ + c * T_CHUNK) * D_HEAD;

    // Stage: relu + cosFormer reweight into LDS
    for (int i = tid; i < T_CHUNK * D_HEAD; i += 256) {
        int l = i >> 6, d = i & 63;
        float kr = fmaxf(k[base + i], 0.f);
        float vr = fmaxf(v[base + i], 0.f);
        int lg = c * T_CHUNK + l;
        float th = HALF_PI * (float)(lg + 1) / (float)L_SEQ;
        float s, cs;
        sincosf(th, &s, &cs);
        k_s[l][pad_col(d)]      = kr * s;
        k_s[l][pad_col(d + 64)] = kr * cs;
        v_s[l][d] = vr;
    }
    __syncthreads();

    const int g = tid & 3, m = tid >> 2;
    float st[32], ks[32];
#pragma unroll
    for (int j = 0; j < 32; ++j) { st[j] = 0.f; ks[j] = 0.f; }

    for (int l = 0; l < T_CHUNK; ++l) {
        float vm = v_s[l][m];
        const float4* kv4 = (const float4*)&k_s[l][36 * g];
#pragma unroll
        for (int jj = 0; jj < 8; ++jj) {
            float4 kk = kv4[jj];
            st[4*jj+0] = fmaf(kk.x, vm, st[4*jj+0]); ks[4*jj+0] += kk.x;
            st[4*jj+1] = fmaf(kk.y, vm, st[4*jj+1]); ks[4*jj+1] += kk.y;
            st[4*jj+2] = fmaf(kk.z, vm, st[4*jj+2]); ks[4*jj+2] += kk.z;
            st[4*jj+3] = fmaf(kk.w, vm, st[4*jj+3]); ks[4*jj+3] += kk.w;
        }
    }

    float* dst = sumkv + (size_t)(n * N_CHUNK + c) * KV_ELEMS;
#pragma unroll
    for (int j = 0; j < 32; ++j) {
        int d2 = 32 * g + j;
        dst[d2 * D_HEAD + m] = st[j];
    }
    if (m == 0) {
        float* dk = sumk + (n * N_CHUNK + c) * D2;
#pragma unroll
        for (int j = 0; j < 32; ++j) dk[32 * g + j] = ks[j];
    }
}

// ---------------------------------------------------------------------------
// K2: per-head exclusive prefix scan over chunks, in place.
// Any element<->thread bijection works; use flat coalesced mapping.
// ---------------------------------------------------------------------------
__global__ __launch_bounds__(256) void k2_prefix(
    float* __restrict__ sumkv, float* __restrict__ sumk)
{
    const int n = blockIdx.x;
    const int tid = threadIdx.x;

    float run[32];
#pragma unroll
    for (int r = 0; r < 32; ++r) run[r] = 0.f;

    float* base = sumkv + (size_t)n * N_CHUNK * KV_ELEMS;
    for (int c = 0; c < N_CHUNK; ++c) {
        float* p = base + (size_t)c * KV_ELEMS;
#pragma unroll
        for (int r = 0; r < 32; ++r) {
            float t = p[tid + 256 * r];
            p[tid + 256 * r] = run[r];
            run[r] += t;
        }
    }

    if (tid < D2) {
        float rk = 0.f;
        float* bk = sumk + n * N_CHUNK * D2;
        for (int c = 0; c < N_CHUNK; ++c) {
            float t = bk[c * D2 + tid];
            bk[c * D2 + tid] = rk;
            rk += t;
        }
    }
}

// ---------------------------------------------------------------------------
// K3: per-(chunk, head): init state from exclusive prefix, sequential walk
// over T positions computing out[l][m] = (q_ . kv_cum[:,m]) / max(q_.k_cum, eps)
// d2 split over 4 lanes (g), reduced with shuffle-xor.
// ---------------------------------------------------------------------------
__global__ __launch_bounds__(256) void k3_output(
    const float* __restrict__ q, const float* __restrict__ k,
    const float* __restrict__ v, const float* __restrict__ sumkv,
    const float* __restrict__ sumk, float* __restrict__ out)
{
    __shared__ float k_s[T_CHUNK][ROWP];
    __shared__ float q_s[T_CHUNK][ROWP];
    __shared__ float v_s[T_CHUNK][D_HEAD];

    const int c = blockIdx.x, n = blockIdx.y;
    const int tid = threadIdx.x;
    const int base = (n * L_SEQ + c * T_CHUNK) * D_HEAD;

    for (int i = tid; i < T_CHUNK * D_HEAD; i += 256) {
        int l = i >> 6, d = i & 63;
        float kr = fmaxf(k[base + i], 0.f);
        float qr = fmaxf(q[base + i], 0.f);
        float vr = fmaxf(v[base + i], 0.f);
        int lg = c * T_CHUNK + l;
        float th = HALF_PI * (float)(lg + 1) / (float)L_SEQ;
        float s, cs;
        sincosf(th, &s, &cs);
        k_s[l][pad_col(d)]      = kr * s;
        k_s[l][pad_col(d + 64)] = kr * cs;
        q_s[l][pad_col(d)]      = qr * s;
        q_s[l][pad_col(d + 64)] = qr * cs;
        v_s[l][d] = vr;
    }
    __syncthreads();

    const int g = tid & 3, m = tid >> 2;

    float st[32], ks[32];
    const float* pkv = sumkv + (size_t)(n * N_CHUNK + c) * KV_ELEMS;
    const float* pk  = sumk + (n * N_CHUNK + c) * D2;
#pragma unroll
    for (int j = 0; j < 32; ++j) {
        st[j] = pkv[(32 * g + j) * D_HEAD + m];
        ks[j] = pk[32 * g + j];
    }

    for (int l = 0; l < T_CHUNK; ++l) {
        float vm = v_s[l][m];
        const float4* kv4 = (const float4*)&k_s[l][36 * g];
        const float4* qv4 = (const float4*)&q_s[l][36 * g];
        float accn0 = 0.f, accn1 = 0.f, accd0 = 0.f, accd1 = 0.f;
#pragma unroll
        for (int jj = 0; jj < 8; ++jj) {
            float4 kk = kv4[jj];
            float4 qq = qv4[jj];
            st[4*jj+0] = fmaf(kk.x, vm, st[4*jj+0]); ks[4*jj+0] += kk.x;
            accn0 = fmaf(qq.x, st[4*jj+0], accn0);
            accd0 = fmaf(qq.x, ks[4*jj+0], accd0);
            st[4*jj+1] = fmaf(kk.y, vm, st[4*jj+1]); ks[4*jj+1] += kk.y;
            accn1 = fmaf(qq.y, st[4*jj+1], accn1);
            accd1 = fmaf(qq.y, ks[4*jj+1], accd1);
            st[4*jj+2] = fmaf(kk.z, vm, st[4*jj+2]); ks[4*jj+2] += kk.z;
            accn0 = fmaf(qq.z, st[4*jj+2], accn0);
            accd0 = fmaf(qq.z, ks[4*jj+2], accd0);
            st[4*jj+3] = fmaf(kk.w, vm, st[4*jj+3]); ks[4*jj+3] += kk.w;
            accn1 = fmaf(qq.w, st[4*jj+3], accn1);
            accd1 = fmaf(qq.w, ks[4*jj+3], accd1);
        }
        float accn = accn0 + accn1;
        float accd = accd0 + accd1;
        accn += __shfl_xor(accn, 1, 64);
        accn += __shfl_xor(accn, 2, 64);
        accd += __shfl_xor(accd, 1, 64);
        accd += __shfl_xor(accd, 2, 64);
        if (g == 0) {
            float den = fmaxf(accd, 1e-6f);
            out[base + l * D_HEAD + m] = accn / den;
        }
    }
}

// ---------------------------------------------------------------------------
extern "C" void kernel_launch(void* const* d_in, const int* in_sizes, int n_in,
                              void* d_out, int out_size, void* d_ws, size_t ws_size,
                              hipStream_t stream) {
    (void)in_sizes; (void)n_in; (void)out_size; (void)ws_size;
    const float* q = (const float*)d_in[0];
    const float* k = (const float*)d_in[1];
    const float* v = (const float*)d_in[2];
    float* out = (float*)d_out;

    float* sumkv = (float*)d_ws;                                   // [N][C][128][64]
    float* sumk  = sumkv + (size_t)N_HEADS * N_CHUNK * KV_ELEMS;   // [N][C][128]

    dim3 grid(N_CHUNK, N_HEADS);
    k1_chunk_sums<<<grid, 256, 0, stream>>>(k, v, sumkv, sumk);
    k2_prefix<<<N_HEADS, 256, 0, stream>>>(sumkv, sumk);
    k3_output<<<grid, 256, 0, stream>>>(q, k, v, sumkv, sumk, out);
}

// Round 2
// 107.577 us; speedup vs baseline: 1.2162x; 1.2162x over previous
//
#include <hip/hip_runtime.h>

// Problem constants (B=2, H=8, L=1024, D=64)
#define N_HEADS 16          // B*H
#define L_SEQ   1024
#define D_HEAD  64
#define D2      128         // 2*D (sin/cos concat)
#define T_CHUNK 32
#define N_CHUNK (L_SEQ / T_CHUNK)   // 32
#define KV_ELEMS (D2 * D_HEAD)      // 8192

// Padded LDS row: insert a 4-float gap every 32 columns so the 4 g-groups
// (float4 reads at 32g-float offsets) land on distinct banks.
#define ROWP 140

__device__ __forceinline__ int pad_col(int d2) { return d2 + 4 * (d2 >> 5); }

#define SINCOS_SCALE 1.53398078788564122971e-3f   // (pi/2)/1024

// ---------------------------------------------------------------------------
// K1: per-(chunk, head) local sums:  sumkv[d2][m] = sum_l k_[l][d2]*v[l][m]
//                                    sumk[d2]     = sum_l k_[l][d2]
// ---------------------------------------------------------------------------
__global__ __launch_bounds__(256) void k1_chunk_sums(
    const float* __restrict__ k, const float* __restrict__ v,
    float* __restrict__ sumkv, float* __restrict__ sumk)
{
    __shared__ float k_s[T_CHUNK][ROWP];
    __shared__ float v_s[T_CHUNK][D_HEAD];

    const int c = blockIdx.x, n = blockIdx.y;
    const int tid = threadIdx.x;
    const int base = (n * L_SEQ + c * T_CHUNK) * D_HEAD;

    // Stage: relu + cosFormer reweight into LDS (8 elements/thread)
    for (int i = tid; i < T_CHUNK * D_HEAD; i += 256) {
        int l = i >> 6, d = i & 63;
        float kr = fmaxf(k[base + i], 0.f);
        float vr = fmaxf(v[base + i], 0.f);
        int lg = c * T_CHUNK + l;
        float th = SINCOS_SCALE * (float)(lg + 1);
        float s = __sinf(th), cs = __cosf(th);
        k_s[l][pad_col(d)]      = kr * s;
        k_s[l][pad_col(d + 64)] = kr * cs;
        v_s[l][d] = vr;
    }
    __syncthreads();

    const int g = tid & 3, m = tid >> 2;
    float st[32], ks[32];
#pragma unroll
    for (int j = 0; j < 32; ++j) { st[j] = 0.f; ks[j] = 0.f; }

    for (int l = 0; l < T_CHUNK; ++l) {
        float vm = v_s[l][m];
        const float4* kv4 = (const float4*)&k_s[l][36 * g];
#pragma unroll
        for (int jj = 0; jj < 8; ++jj) {
            float4 kk = kv4[jj];
            st[4*jj+0] = fmaf(kk.x, vm, st[4*jj+0]); ks[4*jj+0] += kk.x;
            st[4*jj+1] = fmaf(kk.y, vm, st[4*jj+1]); ks[4*jj+1] += kk.y;
            st[4*jj+2] = fmaf(kk.z, vm, st[4*jj+2]); ks[4*jj+2] += kk.z;
            st[4*jj+3] = fmaf(kk.w, vm, st[4*jj+3]); ks[4*jj+3] += kk.w;
        }
    }

    float* dst = sumkv + (size_t)(n * N_CHUNK + c) * KV_ELEMS;
#pragma unroll
    for (int j = 0; j < 32; ++j) {
        int d2 = 32 * g + j;
        dst[d2 * D_HEAD + m] = st[j];
    }
    if (m == 0) {
        float* dk = sumk + (n * N_CHUNK + c) * D2;
#pragma unroll
        for (int j = 0; j < 32; ++j) dk[32 * g + j] = ks[j];
    }
}

// ---------------------------------------------------------------------------
// K2: per-head exclusive prefix scan over chunks, in place.
// 128 blocks: block (s, n) scans elements [s*1024, s*1024+1024) of head n,
// 4 elements per thread for load ILP. Block (0, n) also scans sumk.
// ---------------------------------------------------------------------------
__global__ __launch_bounds__(256) void k2_prefix(
    float* __restrict__ sumkv, float* __restrict__ sumk)
{
    const int s = blockIdx.x;   // 0..7
    const int n = blockIdx.y;   // 0..15
    const int tid = threadIdx.x;

    const int e0 = s * 1024 + tid;   // +0,256,512,768
    float r0 = 0.f, r1 = 0.f, r2 = 0.f, r3 = 0.f;

    float* base = sumkv + (size_t)n * N_CHUNK * KV_ELEMS;
    for (int c = 0; c < N_CHUNK; ++c) {
        float* p = base + (size_t)c * KV_ELEMS + e0;
        float t0 = p[0], t1 = p[256], t2 = p[512], t3 = p[768];
        p[0] = r0; p[256] = r1; p[512] = r2; p[768] = r3;
        r0 += t0; r1 += t1; r2 += t2; r3 += t3;
    }

    if (s == 0 && tid < D2) {
        float rk = 0.f;
        float* bk = sumk + n * N_CHUNK * D2;
        for (int c = 0; c < N_CHUNK; ++c) {
            float t = bk[c * D2 + tid];
            bk[c * D2 + tid] = rk;
            rk += t;
        }
    }
}

// ---------------------------------------------------------------------------
// K3: per-(chunk, head): init state from exclusive prefix, sequential walk
// over T positions computing out[l][m] = (q_ . kv_cum[:,m]) / max(q_.k_cum, eps)
// d2 split over 4 lanes (g), reduced with shuffle-xor.
// ---------------------------------------------------------------------------
__global__ __launch_bounds__(256) void k3_output(
    const float* __restrict__ q, const float* __restrict__ k,
    const float* __restrict__ v, const float* __restrict__ sumkv,
    const float* __restrict__ sumk, float* __restrict__ out)
{
    __shared__ float k_s[T_CHUNK][ROWP];
    __shared__ float q_s[T_CHUNK][ROWP];
    __shared__ float v_s[T_CHUNK][D_HEAD];

    const int c = blockIdx.x, n = blockIdx.y;
    const int tid = threadIdx.x;
    const int base = (n * L_SEQ + c * T_CHUNK) * D_HEAD;

    for (int i = tid; i < T_CHUNK * D_HEAD; i += 256) {
        int l = i >> 6, d = i & 63;
        float kr = fmaxf(k[base + i], 0.f);
        float qr = fmaxf(q[base + i], 0.f);
        float vr = fmaxf(v[base + i], 0.f);
        int lg = c * T_CHUNK + l;
        float th = SINCOS_SCALE * (float)(lg + 1);
        float s = __sinf(th), cs = __cosf(th);
        k_s[l][pad_col(d)]      = kr * s;
        k_s[l][pad_col(d + 64)] = kr * cs;
        q_s[l][pad_col(d)]      = qr * s;
        q_s[l][pad_col(d + 64)] = qr * cs;
        v_s[l][d] = vr;
    }
    __syncthreads();

    const int g = tid & 3, m = tid >> 2;

    float st[32], ks[32];
    const float* pkv = sumkv + (size_t)(n * N_CHUNK + c) * KV_ELEMS;
    const float* pk  = sumk + (n * N_CHUNK + c) * D2;
#pragma unroll
    for (int j = 0; j < 32; ++j) {
        st[j] = pkv[(32 * g + j) * D_HEAD + m];
        ks[j] = pk[32 * g + j];
    }

    for (int l = 0; l < T_CHUNK; ++l) {
        float vm = v_s[l][m];
        const float4* kv4 = (const float4*)&k_s[l][36 * g];
        const float4* qv4 = (const float4*)&q_s[l][36 * g];
        float accn0 = 0.f, accn1 = 0.f, accd0 = 0.f, accd1 = 0.f;
#pragma unroll
        for (int jj = 0; jj < 8; ++jj) {
            float4 kk = kv4[jj];
            float4 qq = qv4[jj];
            st[4*jj+0] = fmaf(kk.x, vm, st[4*jj+0]); ks[4*jj+0] += kk.x;
            accn0 = fmaf(qq.x, st[4*jj+0], accn0);
            accd0 = fmaf(qq.x, ks[4*jj+0], accd0);
            st[4*jj+1] = fmaf(kk.y, vm, st[4*jj+1]); ks[4*jj+1] += kk.y;
            accn1 = fmaf(qq.y, st[4*jj+1], accn1);
            accd1 = fmaf(qq.y, ks[4*jj+1], accd1);
            st[4*jj+2] = fmaf(kk.z, vm, st[4*jj+2]); ks[4*jj+2] += kk.z;
            accn0 = fmaf(qq.z, st[4*jj+2], accn0);
            accd0 = fmaf(qq.z, ks[4*jj+2], accd0);
            st[4*jj+3] = fmaf(kk.w, vm, st[4*jj+3]); ks[4*jj+3] += kk.w;
            accn1 = fmaf(qq.w, st[4*jj+3], accn1);
            accd1 = fmaf(qq.w, ks[4*jj+3], accd1);
        }
        float accn = accn0 + accn1;
        float accd = accd0 + accd1;
        accn += __shfl_xor(accn, 1, 64);
        accn += __shfl_xor(accn, 2, 64);
        accd += __shfl_xor(accd, 1, 64);
        accd += __shfl_xor(accd, 2, 64);
        if (g == 0) {
            float den = fmaxf(accd, 1e-6f);
            out[base + l * D_HEAD + m] = accn / den;
        }
    }
}

// ---------------------------------------------------------------------------
extern "C" void kernel_launch(void* const* d_in, const int* in_sizes, int n_in,
                              void* d_out, int out_size, void* d_ws, size_t ws_size,
                              hipStream_t stream) {
    (void)in_sizes; (void)n_in; (void)out_size; (void)ws_size;
    const float* q = (const float*)d_in[0];
    const float* k = (const float*)d_in[1];
    const float* v = (const float*)d_in[2];
    float* out = (float*)d_out;

    float* sumkv = (float*)d_ws;                                   // [N][C][128][64]
    float* sumk  = sumkv + (size_t)N_HEADS * N_CHUNK * KV_ELEMS;   // [N][C][128]

    dim3 grid(N_CHUNK, N_HEADS);
    k1_chunk_sums<<<grid, 256, 0, stream>>>(k, v, sumkv, sumk);
    dim3 grid2(8, N_HEADS);
    k2_prefix<<<grid2, 256, 0, stream>>>(sumkv, sumk);
    k3_output<<<grid, 256, 0, stream>>>(q, k, v, sumkv, sumk, out);
}